// Round 14
// baseline (71.134 us; speedup 1.0000x reference)
//
#include <hip/hip_runtime.h>
#include <hip/hip_bf16.h>

// GFNet global filter: out = irfft2( rfft2(x) * W ), ortho norm, 14x14 spatial.
// x: (B=256, N=196, C=768) f32 ; W: (14, 8, C, 2) f32 ; out: (B, 196, C) f32.
//
// R14: SPLIT-PATH OUTPUT STORES. R9-R13 wall pinned at ~55us = 150.5MB/2.7TB/s
// -> the nt-store path is the cap (fill kernel proves >=3.8TB/s HBM write).
// Store even-wp rows nt (75MB @ nt path), odd-wp rows cache-allocating (75MB
// lives dirty in the 256MB memory-side L3, rewritten in place each replay ->
// near-zero steady HBM drain). Capacity: x 154 + cached-out 75 = 229 < 256
// -> x stays LLC-resident (R8's full-allocating 150MB thrashed; 75 doesn't).
// Each wave store = 512B uniform-flag region; wp and 14-wp share parity.
//
// Everything else = R13 (best, 55.0us): channel-paired f2 lanes everywhere
// (CB=128, CTILES=6), bf16-packed single-round LDS transposes (57344B,
// 3 barriers), weight-multiply fused into B-loop with JIT float4 weight loads.
// __launch_bounds__(512,2): VGPR budget ~128; R13 measured VGPR=64, no spill.
// Spill tripwire: WRITE_SIZE total must equal 150.5 MB.

static constexpr int CB     = 128;        // channels per block (2 per lane)
static constexpr int NT     = 512;
static constexpr int CTILES = 768 / CB;   // 6

typedef float f2 __attribute__((ext_vector_type(2)));

// cos/sin(2*pi*k/14)
static constexpr float C14[14] = {
     1.0f,
     0.90096886790241915f,  0.62348980185873359f,  0.22252093395631445f,
    -0.22252093395631434f, -0.62348980185873348f, -0.90096886790241915f,
    -1.0f,
    -0.90096886790241926f, -0.62348980185873371f, -0.22252093395631456f,
     0.22252093395631423f,  0.62348980185873337f,  0.90096886790241904f
};
static constexpr float S14[14] = {
     0.0f,
     0.43388373911755812f,  0.78183148246802980f,  0.97492791218182362f,
     0.97492791218182362f,  0.78183148246802991f,  0.43388373911755823f,
     0.0f,
    -0.43388373911755806f, -0.78183148246802958f, -0.97492791218182362f,
    -0.97492791218182373f, -0.78183148246802991f, -0.43388373911755834f
};

__device__ __forceinline__ f2 mk2(float a, float b) { f2 r; r.x = a; r.y = b; return r; }
__device__ __forceinline__ f2 sp2(float a)          { f2 r; r.x = a; r.y = a; return r; }
__device__ __forceinline__ f2 fma2(f2 a, float c, f2 acc) {
    return __builtin_elementwise_fma(a, sp2(c), acc);
}
__device__ __forceinline__ f2 fmav(f2 a, f2 b, f2 acc) {
    return __builtin_elementwise_fma(a, b, acc);
}

__device__ __forceinline__ uint32_t pk1(float re, float im) {
    union { __hip_bfloat162 h2; uint32_t u; } cv;
    cv.h2 = __float22bfloat162_rn(make_float2(re, im));
    return cv.u;
}
__device__ __forceinline__ uint2 pk2(f2 re, f2 im) {
    uint2 r; r.x = pk1(re.x, im.x); r.y = pk1(re.y, im.y); return r;
}
__device__ __forceinline__ f2 up_lo(uint2 v) {   // re of both channels
    return mk2(__uint_as_float(v.x << 16), __uint_as_float(v.y << 16));
}
__device__ __forceinline__ f2 up_hi(uint2 v) {   // im of both channels
    return mk2(__uint_as_float(v.x & 0xffff0000u), __uint_as_float(v.y & 0xffff0000u));
}

// split-path store: nt for even wp, cache-allocating for odd wp
__device__ __forceinline__ void st_mix(f2 v, float* p, bool nt) {
    if (nt) __builtin_nontemporal_store(v, reinterpret_cast<f2*>(p));
    else    *reinterpret_cast<f2*>(p) = v;
}

// ---------------- phase A: rfft along w for one row (channel-pair lanes) ----------------
__device__ __forceinline__ void phaseA(const f2 v[14], f2 Ar[8], f2 Ai[7]) {
    f2 s[7], d[7];
    #pragma unroll
    for (int j = 1; j <= 6; ++j) { s[j] = v[j] + v[14 - j]; d[j] = v[j] - v[14 - j]; }
    const f2 p = v[0] + v[7], q = v[0] - v[7];
    Ar[0] = p + s[1] + s[2] + s[3] + s[4] + s[5] + s[6];
    Ar[7] = q - s[1] + s[2] - s[3] + s[4] - s[5] + s[6];
    #pragma unroll
    for (int u = 1; u <= 6; ++u) {
        f2 re = (u & 1) ? q : p;
        f2 im = sp2(0.f);
        #pragma unroll
        for (int j = 1; j <= 6; ++j) {
            re = fma2(s[j],  C14[(u * j) % 14], re);
            im = fma2(d[j], -S14[(u * j) % 14], im);
        }
        Ar[u] = re; Ai[u] = im;
    }
}

// ---------------- phase D + split-path stores for one row ----------------
__device__ __forceinline__ void phaseD_row(const uint2* T2, float* ob, int row, int ln) {
    f2 a0[8], b0v[7];
    #pragma unroll
    for (int v = 0; v < 8; ++v) {
        const uint2 t = T2[(row * 8 + v) * 64 + ln];
        const float beta = (v == 0 || v == 7) ? (1.0f / 196.0f) : (2.0f / 196.0f);
        a0[v] = up_lo(t) * sp2(beta);
        if (v >= 1 && v <= 6) b0v[v] = up_hi(t) * sp2(2.0f / 196.0f);
    }
    const f2 pp = a0[0] + a0[7], qq = a0[0] - a0[7];
    const f2 o0 = pp + a0[1] + a0[2] + a0[3] + a0[4] + a0[5] + a0[6];
    const f2 o7 = qq - a0[1] + a0[2] - a0[3] + a0[4] - a0[5] + a0[6];
    st_mix(o0, ob + (size_t)(row * 14 + 0) * 768, true);    // wp=0 even -> nt
    st_mix(o7, ob + (size_t)(row * 14 + 7) * 768, false);   // wp=7 odd  -> cached
    #pragma unroll
    for (int wp = 1; wp <= 6; ++wp) {
        f2 t1 = (wp & 1) ? qq : pp;
        f2 t2 = sp2(0.f);
        #pragma unroll
        for (int v = 1; v <= 6; ++v) {
            t1 = fma2(a0[v],  C14[(v * wp) % 14], t1);
            t2 = fma2(b0v[v], S14[(v * wp) % 14], t2);
        }
        const bool ntf = ((wp & 1) == 0);                   // wp and 14-wp share parity
        st_mix(t1 - t2, ob + (size_t)(row * 14 + wp) * 768,      ntf);
        st_mix(t1 + t2, ob + (size_t)(row * 14 + 14 - wp) * 768, ntf);
    }
}

__global__ __launch_bounds__(NT, 2) void gfnet_filter(
    const float* __restrict__ x,
    const float* __restrict__ wgt,
    float* __restrict__ out)
{
    // 57344 B union buffer, uint2 = packed bf16 complex for 2 channels:
    //   G round: [h=0..13][u=0..7][64]   P round: [row=0..13][v=0..7][64]
    __shared__ uint2 T2[14 * 8 * 64];

    const int bid = blockIdx.x;
    const int b   = bid / CTILES;
    const int ct  = bid - b * CTILES;
    const int c0  = ct * CB;
    const int tid = threadIdx.x;
    const int wv  = tid >> 6;
    const int ln  = tid & 63;
    const bool two = (wv < 6);
    const int r0 = wv;          // rows handled in phases A/D
    const int r1 = wv + 8;

    const float* xb = x + (size_t)b * 196 * 768 + c0 + 2 * ln;

    // ---------------- x loads (float2 per lane, both rows issued up front) ----------------
    f2 v0[14], v1[14];
    #pragma unroll
    for (int w = 0; w < 14; ++w)
        v0[w] = *reinterpret_cast<const f2*>(xb + (size_t)(r0 * 14 + w) * 768);
    if (two) {
        #pragma unroll
        for (int w = 0; w < 14; ++w)
            v1[w] = *reinterpret_cast<const f2*>(xb + (size_t)(r1 * 14 + w) * 768);
    }

    // ---------------- phase A + G transpose (packed bf16, single round) ----------------
    {
        f2 Ar[8], Ai[7];
        phaseA(v0, Ar, Ai);
        #pragma unroll
        for (int u = 0; u < 8; ++u)
            T2[(r0 * 8 + u) * 64 + ln] = pk2(Ar[u], (u >= 1 && u <= 6) ? Ai[u] : sp2(0.f));
        if (two) {
            phaseA(v1, Ar, Ai);
            #pragma unroll
            for (int u = 0; u < 8; ++u)
                T2[(r1 * 8 + u) * 64 + ln] = pk2(Ar[u], (u >= 1 && u <= 6) ? Ai[u] : sp2(0.f));
        }
    }

    __syncthreads();                    // bar1: G visible

    f2 gr[14], gi[14];
    #pragma unroll
    for (int h = 0; h < 14; ++h) {
        const uint2 t = T2[(h * 8 + wv) * 64 + ln];
        gr[h] = up_lo(t); gi[h] = up_hi(t);
    }

    // ---------------- phase B fused with weight multiply (JIT float4 weight loads) ----------------
    f2 esr[3], esi[3], edr[3], edi[3], osr[3], osi[3], odr[3], odi[3];
    #pragma unroll
    for (int i = 0; i < 3; ++i) {
        int j = 2 * (i + 1);
        esr[i] = gr[j] + gr[14 - j]; esi[i] = gi[j] + gi[14 - j];
        edr[i] = gr[j] - gr[14 - j]; edi[i] = gi[j] - gi[14 - j];
        j = 2 * i + 1;
        osr[i] = gr[j] + gr[14 - j]; osi[i] = gi[j] + gi[14 - j];
        odr[i] = gr[j] - gr[14 - j]; odi[i] = gi[j] - gi[14 - j];
    }
    const f2 g0r = gr[0], g0i = gi[0], g7r = gr[7], g7i = gi[7];

    // weights: (14, 8, C, 2); float4 covers {re(c), im(c), re(c+1), im(c+1)}
    const float* wbase = wgt + ((size_t)wv * 768 + c0 + 2 * ln) * 2;

    f2 Hr[14], Hi[14];
    #pragma unroll
    for (int k = 0; k < 7; ++k) {
        const float4 wA = *reinterpret_cast<const float4*>(wbase + (size_t)k       * (8 * 768 * 2));
        const float4 wB = *reinterpret_cast<const float4*>(wbase + (size_t)(k + 7) * (8 * 768 * 2));
        f2 er, ei, onr, oni;
        if (k == 0) {
            er  = g0r + esr[0] + esr[1] + esr[2];
            ei  = g0i + esi[0] + esi[1] + esi[2];
            onr = g7r + osr[0] + osr[1] + osr[2];
            oni = g7i + osi[0] + osi[1] + osi[2];
        } else {
            er = g0r; ei = g0i;
            #pragma unroll
            for (int i = 0; i < 3; ++i) {
                const int j = 2 * (i + 1);
                const float c = C14[(j * k) % 14], s2 = S14[(j * k) % 14];
                er = fma2(esr[i], c, er); er = fma2(edi[i],  s2, er);
                ei = fma2(esi[i], c, ei); ei = fma2(edr[i], -s2, ei);
            }
            onr = (k & 1) ? -g7r : g7r;
            oni = (k & 1) ? -g7i : g7i;
            #pragma unroll
            for (int i = 0; i < 3; ++i) {
                const int j = 2 * i + 1;
                const float c = C14[(j * k) % 14], s2 = S14[(j * k) % 14];
                onr = fma2(osr[i], c, onr); onr = fma2(odi[i],  s2, onr);
                oni = fma2(osi[i], c, oni); oni = fma2(odr[i], -s2, oni);
            }
        }
        const f2 ar = er + onr, ai = ei + oni;
        const f2 br = er - onr, bi = ei - oni;
        const f2 wAr = mk2(wA.x, wA.z), wAi = mk2(wA.y, wA.w);
        const f2 wBr = mk2(wB.x, wB.z), wBi = mk2(wB.y, wB.w);
        Hr[k]     = fmav(ar, wAr, -(ai * wAi));
        Hi[k]     = fmav(ar, wAi,   ai * wAr);
        Hr[k + 7] = fmav(br, wBr, -(bi * wBi));
        Hi[k + 7] = fmav(br, wBi,   bi * wBr);
    }

    // ---------------- phase C: P = IFFT_h(H), radix-2 + pairing ----------------
    f2 qsr[3], qsi[3], qdr[3], qdi[3], rsr[3], rsi[3], rdr[3], rdi[3];
    #pragma unroll
    for (int i = 0; i < 3; ++i) {
        int j = 2 * (i + 1);
        qsr[i] = Hr[j] + Hr[14 - j]; qsi[i] = Hi[j] + Hi[14 - j];
        qdr[i] = Hr[j] - Hr[14 - j]; qdi[i] = Hi[j] - Hi[14 - j];
        j = 2 * i + 1;
        rsr[i] = Hr[j] + Hr[14 - j]; rsi[i] = Hi[j] + Hi[14 - j];
        rdr[i] = Hr[j] - Hr[14 - j]; rdi[i] = Hi[j] - Hi[14 - j];
    }
    f2 Qr[7], Qi[7], Rr[7], Ri[7];
    Qr[0] = Hr[0] + qsr[0] + qsr[1] + qsr[2];
    Qi[0] = Hi[0] + qsi[0] + qsi[1] + qsi[2];
    Rr[0] = Hr[7] + rsr[0] + rsr[1] + rsr[2];
    Ri[0] = Hi[7] + rsi[0] + rsi[1] + rsi[2];
    #pragma unroll
    for (int m = 1; m <= 6; ++m) {
        f2 qr = Hr[0], qi2 = Hi[0];
        #pragma unroll
        for (int i = 0; i < 3; ++i) {
            const int j = 2 * (i + 1);
            const float c = C14[(j * m) % 14], s2 = S14[(j * m) % 14];
            qr  = fma2(qsr[i], c, qr);  qr  = fma2(qdi[i], -s2, qr);
            qi2 = fma2(qsi[i], c, qi2); qi2 = fma2(qdr[i],  s2, qi2);
        }
        Qr[m] = qr; Qi[m] = qi2;
        f2 rr = (m & 1) ? -Hr[7] : Hr[7];
        f2 ri2 = (m & 1) ? -Hi[7] : Hi[7];
        #pragma unroll
        for (int i = 0; i < 3; ++i) {
            const int j = 2 * i + 1;
            const float c = C14[(j * m) % 14], s2 = S14[(j * m) % 14];
            rr  = fma2(rsr[i], c, rr);  rr  = fma2(rdi[i], -s2, rr);
            ri2 = fma2(rsi[i], c, ri2); ri2 = fma2(rdr[i],  s2, ri2);
        }
        Rr[m] = rr; Ri[m] = ri2;
    }

    __syncthreads();                    // bar2: all G reads done (convergent)

    // ---------------- P transpose (packed bf16, single round) ----------------
    #pragma unroll
    for (int m = 0; m < 7; ++m) {
        T2[(m * 8 + wv) * 64 + ln]       = pk2(Qr[m] + Rr[m], Qi[m] + Ri[m]);
        T2[((m + 7) * 8 + wv) * 64 + ln] = pk2(Qr[m] - Rr[m], Qi[m] - Ri[m]);
    }
    __syncthreads();                    // bar3: P visible

    // ---------------- phase D + split-path stores ----------------
    float* ob = out + (size_t)b * 196 * 768 + c0 + 2 * ln;
    phaseD_row(T2, ob, r0, ln);
    if (two) phaseD_row(T2, ob, r1, ln);
}

extern "C" void kernel_launch(void* const* d_in, const int* in_sizes, int n_in,
                              void* d_out, int out_size, void* d_ws, size_t ws_size,
                              hipStream_t stream) {
    const float* x   = (const float*)d_in[0];
    const float* wgt = (const float*)d_in[1];
    float*       o   = (float*)d_out;

    const int B = in_sizes[0] / (196 * 768);   // 256
    dim3 grid(B * CTILES), block(NT);
    gfnet_filter<<<grid, block, 0, stream>>>(x, wgt, o);
}

// Round 15
// 57.210 us; speedup vs baseline: 1.2434x; 1.2434x over previous
//
#include <hip/hip_runtime.h>
#include <hip/hip_bf16.h>

// GFNet global filter: out = irfft2( rfft2(x) * W ), ortho norm, 14x14 spatial.
// x: (B=256, N=196, C=768) f32 ; W: (14, 8, C, 2) f32 ; out: (B, 196, C) f32.
//
// R15 = R13 (best, 55.0us), reverted after R14's split-path store experiment
// regressed to 71us and completed the memory model:
//   steady HBM traffic = x reads 154MB + nt-writes 150.5MB = 304.5MB at the
//   mixed-R/W sustained rate ~5.5 TB/s (88% of the 6.29 TB/s read-only
//   ceiling) -> 55us. Predicts R8 (cached stores, +75MB pollution) = 69us ✓,
//   R9-R13 = 55-57us ✓, R14 (half-cached) = ~70us ✓. Compute (24-42us VALU
//   busy across R10-R13) never moved the wall -> fully hidden under memory.
//   Both streams are irreducible -> this is the memory roofline.
//
// Structure: channel-paired f2 lanes everywhere (CB=128, CTILES=6) - every
// op processes 2 independent channels per pk-instruction; bf16-packed
// single-round LDS transposes (57344B, 3 barriers); weight-multiply fused
// into the B k-loop with JIT float4 weight loads (L2-resident); full
// non-temporal output stores (cached stores evict x from the 256MB LLC).
// __launch_bounds__(512,2): VGPR budget ~128; measures 64, no spill.

static constexpr int CB     = 128;        // channels per block (2 per lane)
static constexpr int NT     = 512;
static constexpr int CTILES = 768 / CB;   // 6

typedef float f2 __attribute__((ext_vector_type(2)));

// cos/sin(2*pi*k/14)
static constexpr float C14[14] = {
     1.0f,
     0.90096886790241915f,  0.62348980185873359f,  0.22252093395631445f,
    -0.22252093395631434f, -0.62348980185873348f, -0.90096886790241915f,
    -1.0f,
    -0.90096886790241926f, -0.62348980185873371f, -0.22252093395631456f,
     0.22252093395631423f,  0.62348980185873337f,  0.90096886790241904f
};
static constexpr float S14[14] = {
     0.0f,
     0.43388373911755812f,  0.78183148246802980f,  0.97492791218182362f,
     0.97492791218182362f,  0.78183148246802991f,  0.43388373911755823f,
     0.0f,
    -0.43388373911755806f, -0.78183148246802958f, -0.97492791218182362f,
    -0.97492791218182373f, -0.78183148246802991f, -0.43388373911755834f
};

__device__ __forceinline__ f2 mk2(float a, float b) { f2 r; r.x = a; r.y = b; return r; }
__device__ __forceinline__ f2 sp2(float a)          { f2 r; r.x = a; r.y = a; return r; }
__device__ __forceinline__ f2 fma2(f2 a, float c, f2 acc) {
    return __builtin_elementwise_fma(a, sp2(c), acc);
}
__device__ __forceinline__ f2 fmav(f2 a, f2 b, f2 acc) {
    return __builtin_elementwise_fma(a, b, acc);
}

__device__ __forceinline__ uint32_t pk1(float re, float im) {
    union { __hip_bfloat162 h2; uint32_t u; } cv;
    cv.h2 = __float22bfloat162_rn(make_float2(re, im));
    return cv.u;
}
__device__ __forceinline__ uint2 pk2(f2 re, f2 im) {
    uint2 r; r.x = pk1(re.x, im.x); r.y = pk1(re.y, im.y); return r;
}
__device__ __forceinline__ f2 up_lo(uint2 v) {   // re of both channels
    return mk2(__uint_as_float(v.x << 16), __uint_as_float(v.y << 16));
}
__device__ __forceinline__ f2 up_hi(uint2 v) {   // im of both channels
    return mk2(__uint_as_float(v.x & 0xffff0000u), __uint_as_float(v.y & 0xffff0000u));
}

// ---------------- phase A: rfft along w for one row (channel-pair lanes) ----------------
__device__ __forceinline__ void phaseA(const f2 v[14], f2 Ar[8], f2 Ai[7]) {
    f2 s[7], d[7];
    #pragma unroll
    for (int j = 1; j <= 6; ++j) { s[j] = v[j] + v[14 - j]; d[j] = v[j] - v[14 - j]; }
    const f2 p = v[0] + v[7], q = v[0] - v[7];
    Ar[0] = p + s[1] + s[2] + s[3] + s[4] + s[5] + s[6];
    Ar[7] = q - s[1] + s[2] - s[3] + s[4] - s[5] + s[6];
    #pragma unroll
    for (int u = 1; u <= 6; ++u) {
        f2 re = (u & 1) ? q : p;
        f2 im = sp2(0.f);
        #pragma unroll
        for (int j = 1; j <= 6; ++j) {
            re = fma2(s[j],  C14[(u * j) % 14], re);
            im = fma2(d[j], -S14[(u * j) % 14], im);
        }
        Ar[u] = re; Ai[u] = im;
    }
}

// ---------------- phase D + nt stores for one row ----------------
__device__ __forceinline__ void phaseD_row(const uint2* T2, float* ob, int row, int ln) {
    f2 a0[8], b0v[7];
    #pragma unroll
    for (int v = 0; v < 8; ++v) {
        const uint2 t = T2[(row * 8 + v) * 64 + ln];
        const float beta = (v == 0 || v == 7) ? (1.0f / 196.0f) : (2.0f / 196.0f);
        a0[v] = up_lo(t) * sp2(beta);
        if (v >= 1 && v <= 6) b0v[v] = up_hi(t) * sp2(2.0f / 196.0f);
    }
    const f2 pp = a0[0] + a0[7], qq = a0[0] - a0[7];
    const f2 o0 = pp + a0[1] + a0[2] + a0[3] + a0[4] + a0[5] + a0[6];
    const f2 o7 = qq - a0[1] + a0[2] - a0[3] + a0[4] - a0[5] + a0[6];
    __builtin_nontemporal_store(o0, reinterpret_cast<f2*>(ob + (size_t)(row * 14 + 0) * 768));
    __builtin_nontemporal_store(o7, reinterpret_cast<f2*>(ob + (size_t)(row * 14 + 7) * 768));
    #pragma unroll
    for (int wp = 1; wp <= 6; ++wp) {
        f2 t1 = (wp & 1) ? qq : pp;
        f2 t2 = sp2(0.f);
        #pragma unroll
        for (int v = 1; v <= 6; ++v) {
            t1 = fma2(a0[v],  C14[(v * wp) % 14], t1);
            t2 = fma2(b0v[v], S14[(v * wp) % 14], t2);
        }
        __builtin_nontemporal_store(t1 - t2,
            reinterpret_cast<f2*>(ob + (size_t)(row * 14 + wp) * 768));
        __builtin_nontemporal_store(t1 + t2,
            reinterpret_cast<f2*>(ob + (size_t)(row * 14 + 14 - wp) * 768));
    }
}

__global__ __launch_bounds__(NT, 2) void gfnet_filter(
    const float* __restrict__ x,
    const float* __restrict__ wgt,
    float* __restrict__ out)
{
    // 57344 B union buffer, uint2 = packed bf16 complex for 2 channels:
    //   G round: [h=0..13][u=0..7][64]   P round: [row=0..13][v=0..7][64]
    __shared__ uint2 T2[14 * 8 * 64];

    const int bid = blockIdx.x;
    const int b   = bid / CTILES;
    const int ct  = bid - b * CTILES;
    const int c0  = ct * CB;
    const int tid = threadIdx.x;
    const int wv  = tid >> 6;
    const int ln  = tid & 63;
    const bool two = (wv < 6);
    const int r0 = wv;          // rows handled in phases A/D
    const int r1 = wv + 8;

    const float* xb = x + (size_t)b * 196 * 768 + c0 + 2 * ln;

    // ---------------- x loads (float2 per lane, both rows issued up front) ----------------
    f2 v0[14], v1[14];
    #pragma unroll
    for (int w = 0; w < 14; ++w)
        v0[w] = *reinterpret_cast<const f2*>(xb + (size_t)(r0 * 14 + w) * 768);
    if (two) {
        #pragma unroll
        for (int w = 0; w < 14; ++w)
            v1[w] = *reinterpret_cast<const f2*>(xb + (size_t)(r1 * 14 + w) * 768);
    }

    // ---------------- phase A + G transpose (packed bf16, single round) ----------------
    {
        f2 Ar[8], Ai[7];
        phaseA(v0, Ar, Ai);
        #pragma unroll
        for (int u = 0; u < 8; ++u)
            T2[(r0 * 8 + u) * 64 + ln] = pk2(Ar[u], (u >= 1 && u <= 6) ? Ai[u] : sp2(0.f));
        if (two) {
            phaseA(v1, Ar, Ai);
            #pragma unroll
            for (int u = 0; u < 8; ++u)
                T2[(r1 * 8 + u) * 64 + ln] = pk2(Ar[u], (u >= 1 && u <= 6) ? Ai[u] : sp2(0.f));
        }
    }

    __syncthreads();                    // bar1: G visible

    f2 gr[14], gi[14];
    #pragma unroll
    for (int h = 0; h < 14; ++h) {
        const uint2 t = T2[(h * 8 + wv) * 64 + ln];
        gr[h] = up_lo(t); gi[h] = up_hi(t);
    }

    // ---------------- phase B fused with weight multiply (JIT float4 weight loads) ----------------
    f2 esr[3], esi[3], edr[3], edi[3], osr[3], osi[3], odr[3], odi[3];
    #pragma unroll
    for (int i = 0; i < 3; ++i) {
        int j = 2 * (i + 1);
        esr[i] = gr[j] + gr[14 - j]; esi[i] = gi[j] + gi[14 - j];
        edr[i] = gr[j] - gr[14 - j]; edi[i] = gi[j] - gi[14 - j];
        j = 2 * i + 1;
        osr[i] = gr[j] + gr[14 - j]; osi[i] = gi[j] + gi[14 - j];
        odr[i] = gr[j] - gr[14 - j]; odi[i] = gi[j] - gi[14 - j];
    }
    const f2 g0r = gr[0], g0i = gi[0], g7r = gr[7], g7i = gi[7];

    // weights: (14, 8, C, 2); float4 covers {re(c), im(c), re(c+1), im(c+1)}
    const float* wbase = wgt + ((size_t)wv * 768 + c0 + 2 * ln) * 2;

    f2 Hr[14], Hi[14];
    #pragma unroll
    for (int k = 0; k < 7; ++k) {
        const float4 wA = *reinterpret_cast<const float4*>(wbase + (size_t)k       * (8 * 768 * 2));
        const float4 wB = *reinterpret_cast<const float4*>(wbase + (size_t)(k + 7) * (8 * 768 * 2));
        f2 er, ei, onr, oni;
        if (k == 0) {
            er  = g0r + esr[0] + esr[1] + esr[2];
            ei  = g0i + esi[0] + esi[1] + esi[2];
            onr = g7r + osr[0] + osr[1] + osr[2];
            oni = g7i + osi[0] + osi[1] + osi[2];
        } else {
            er = g0r; ei = g0i;
            #pragma unroll
            for (int i = 0; i < 3; ++i) {
                const int j = 2 * (i + 1);
                const float c = C14[(j * k) % 14], s2 = S14[(j * k) % 14];
                er = fma2(esr[i], c, er); er = fma2(edi[i],  s2, er);
                ei = fma2(esi[i], c, ei); ei = fma2(edr[i], -s2, ei);
            }
            onr = (k & 1) ? -g7r : g7r;
            oni = (k & 1) ? -g7i : g7i;
            #pragma unroll
            for (int i = 0; i < 3; ++i) {
                const int j = 2 * i + 1;
                const float c = C14[(j * k) % 14], s2 = S14[(j * k) % 14];
                onr = fma2(osr[i], c, onr); onr = fma2(odi[i],  s2, onr);
                oni = fma2(osi[i], c, oni); oni = fma2(odr[i], -s2, oni);
            }
        }
        const f2 ar = er + onr, ai = ei + oni;
        const f2 br = er - onr, bi = ei - oni;
        const f2 wAr = mk2(wA.x, wA.z), wAi = mk2(wA.y, wA.w);
        const f2 wBr = mk2(wB.x, wB.z), wBi = mk2(wB.y, wB.w);
        Hr[k]     = fmav(ar, wAr, -(ai * wAi));
        Hi[k]     = fmav(ar, wAi,   ai * wAr);
        Hr[k + 7] = fmav(br, wBr, -(bi * wBi));
        Hi[k + 7] = fmav(br, wBi,   bi * wBr);
    }

    // ---------------- phase C: P = IFFT_h(H), radix-2 + pairing ----------------
    f2 qsr[3], qsi[3], qdr[3], qdi[3], rsr[3], rsi[3], rdr[3], rdi[3];
    #pragma unroll
    for (int i = 0; i < 3; ++i) {
        int j = 2 * (i + 1);
        qsr[i] = Hr[j] + Hr[14 - j]; qsi[i] = Hi[j] + Hi[14 - j];
        qdr[i] = Hr[j] - Hr[14 - j]; qdi[i] = Hi[j] - Hi[14 - j];
        j = 2 * i + 1;
        rsr[i] = Hr[j] + Hr[14 - j]; rsi[i] = Hi[j] + Hi[14 - j];
        rdr[i] = Hr[j] - Hr[14 - j]; rdi[i] = Hi[j] - Hi[14 - j];
    }
    f2 Qr[7], Qi[7], Rr[7], Ri[7];
    Qr[0] = Hr[0] + qsr[0] + qsr[1] + qsr[2];
    Qi[0] = Hi[0] + qsi[0] + qsi[1] + qsi[2];
    Rr[0] = Hr[7] + rsr[0] + rsr[1] + rsr[2];
    Ri[0] = Hi[7] + rsi[0] + rsi[1] + rsi[2];
    #pragma unroll
    for (int m = 1; m <= 6; ++m) {
        f2 qr = Hr[0], qi2 = Hi[0];
        #pragma unroll
        for (int i = 0; i < 3; ++i) {
            const int j = 2 * (i + 1);
            const float c = C14[(j * m) % 14], s2 = S14[(j * m) % 14];
            qr  = fma2(qsr[i], c, qr);  qr  = fma2(qdi[i], -s2, qr);
            qi2 = fma2(qsi[i], c, qi2); qi2 = fma2(qdr[i],  s2, qi2);
        }
        Qr[m] = qr; Qi[m] = qi2;
        f2 rr = (m & 1) ? -Hr[7] : Hr[7];
        f2 ri2 = (m & 1) ? -Hi[7] : Hi[7];
        #pragma unroll
        for (int i = 0; i < 3; ++i) {
            const int j = 2 * i + 1;
            const float c = C14[(j * m) % 14], s2 = S14[(j * m) % 14];
            rr  = fma2(rsr[i], c, rr);  rr  = fma2(rdi[i], -s2, rr);
            ri2 = fma2(rsi[i], c, ri2); ri2 = fma2(rdr[i],  s2, ri2);
        }
        Rr[m] = rr; Ri[m] = ri2;
    }

    __syncthreads();                    // bar2: all G reads done (convergent)

    // ---------------- P transpose (packed bf16, single round) ----------------
    #pragma unroll
    for (int m = 0; m < 7; ++m) {
        T2[(m * 8 + wv) * 64 + ln]       = pk2(Qr[m] + Rr[m], Qi[m] + Ri[m]);
        T2[((m + 7) * 8 + wv) * 64 + ln] = pk2(Qr[m] - Rr[m], Qi[m] - Ri[m]);
    }
    __syncthreads();                    // bar3: P visible

    // ---------------- phase D + nt stores ----------------
    float* ob = out + (size_t)b * 196 * 768 + c0 + 2 * ln;
    phaseD_row(T2, ob, r0, ln);
    if (two) phaseD_row(T2, ob, r1, ln);
}

extern "C" void kernel_launch(void* const* d_in, const int* in_sizes, int n_in,
                              void* d_out, int out_size, void* d_ws, size_t ws_size,
                              hipStream_t stream) {
    const float* x   = (const float*)d_in[0];
    const float* wgt = (const float*)d_in[1];
    float*       o   = (float*)d_out;

    const int B = in_sizes[0] / (196 * 768);   // 256
    dim3 grid(B * CTILES), block(NT);
    gfnet_filter<<<grid, block, 0, stream>>>(x, wgt, o);
}